// Round 4
// baseline (357.953 us; speedup 1.0000x reference)
//
#include <hip/hip_runtime.h>

#define B_  4
#define N_  512
#define M_  512
#define D_  128
#define H_  128
#define EPS 1e-5f

typedef __attribute__((ext_vector_type(8))) short short8;
typedef __attribute__((ext_vector_type(4))) float f32x4;
typedef __attribute__((ext_vector_type(4))) unsigned u32x4;

__device__ __forceinline__ unsigned short f2bf(float f){
  unsigned u = __float_as_uint(f);
  u += 0x7fffu + ((u >> 16) & 1u);          // round-to-nearest-even
  return (unsigned short)(u >> 16);
}
__device__ __forceinline__ float bf2f(unsigned short s){
  return __uint_as_float(((unsigned)s) << 16);
}

// hi/lo bf16 split of |d0|,|d1| packed into dwords.
__device__ __forceinline__ void split2(float d0, float d1, unsigned &hp, unsigned &lp){
  unsigned a0 = __float_as_uint(d0) & 0x7fffffffu;   // |d|
  unsigned a1 = __float_as_uint(d1) & 0x7fffffffu;
  unsigned r0 = a0 + 0x8000u;                        // round half up to bf16
  unsigned r1 = a1 + 0x8000u;
  hp = __builtin_amdgcn_perm(r1, r0, 0x07060302u);   // pack top16(r0)|top16(r1)
  float lo0 = __uint_as_float(a0) - __uint_as_float(r0 & 0xffff0000u);
  float lo1 = __uint_as_float(a1) - __uint_as_float(r1 & 0xffff0000u);
  unsigned t;
  asm("v_cvt_pk_bf16_f32 %0, %1, %2" : "=v"(t) : "v"(lo0), "v"(lo1));
  lp = t;
}

// ---------------- merged prep ----------------
__global__ __launch_bounds__(256) void prep_all(
    const float* __restrict__ x, const float* __restrict__ y,
    const float* __restrict__ W1, const float* __restrict__ b1,
    float* __restrict__ cx, float* __restrict__ cy,
    unsigned short* __restrict__ bhi, unsigned short* __restrict__ blo)
{
  const int blk = blockIdx.x;
  if (blk < 2048) {
    const int row = blk * 2 + (threadIdx.x >> 7);   // 0..4095
    const int h = threadIdx.x & 127;
    const bool isX = row < B_ * N_;
    const int r = isX ? row : row - B_ * N_;
    const float* src = (isX ? x : y) + (size_t)r * D_;
    const float* W = W1 + (isX ? 0 : D_ * H_);
    float acc = isX ? b1[h] : 0.f;
#pragma unroll
    for (int d0 = 0; d0 < D_; d0 += 4) {
      const f32x4 s = *(const f32x4*)(src + d0);
      acc = fmaf(s.x, W[(d0 + 0) * H_ + h], acc);
      acc = fmaf(s.y, W[(d0 + 1) * H_ + h], acc);
      acc = fmaf(s.z, W[(d0 + 2) * H_ + h], acc);
      acc = fmaf(s.w, W[(d0 + 3) * H_ + h], acc);
    }
    (isX ? cx : cy)[(size_t)r * H_ + h] = acc;
  } else {
    const int t = (blk - 2048) * 256 + threadIdx.x;   // 0..16383
    const int i    = t & 7;
    const int lane = (t >> 3) & 63;
    const int ht   = (t >> 9) & 7;
    const int ks   = t >> 12;
    const int k = ks * 32 + ((lane >> 4) << 3) + i;
    const int h = ht * 16 + (lane & 15);
    const float v = W1[(size_t)(2 * D_ + k) * H_ + h];
    const unsigned short hi = f2bf(v);
    bhi[t] = hi;
    blo[t] = f2bf(v - bf2f(hi));
  }
}

// ---------------- main fused kernel ----------------
// grid: (mblock=4, npair=256, b=4), 512 threads = 8 waves.
// waves 0-3 -> n = 2*npair, waves 4-7 -> n = 2*npair+1 (shared LDS B-stage).
// OPERAND-SWAPPED MFMA: D[h,m] = W1d^T x diff^T, so lane holds 32 h-values
// for one m -> LayerNorm reduction is lane-local + 2 shfl.
__global__ __launch_bounds__(512, 4) void fused_main(
    const float* __restrict__ x, const float* __restrict__ y,
    const float* __restrict__ gamma, const float* __restrict__ beta,
    const float* __restrict__ W2, const float* __restrict__ b2,
    const float* __restrict__ cx, const float* __restrict__ cy,
    const unsigned short* __restrict__ bhi, float* __restrict__ out)
{
  __shared__ char smem[65536];           // [hi 32KB][lo 32KB] fragment order

  const int tid = threadIdx.x;
  const int mblock = blockIdx.x, b = blockIdx.z;

  {
    const f32x4* src = (const f32x4*)bhi;   // bhi||blo contiguous 64KB
    f32x4* dst = (f32x4*)smem;
#pragma unroll
    for (int i = 0; i < 8; ++i)
      dst[i * 512 + tid] = src[i * 512 + tid];
  }
  __syncthreads();

  const int wave = tid >> 6, lane = tid & 63, g = lane >> 4, c = lane & 15;
  const int n = blockIdx.y * 2 + (wave >> 2);
  const int m0 = mblock * 128 + (wave & 3) * 32;
  const float* xrow = x + (size_t)(b * N_ + n) * D_;

  f32x4 acc[2][8];
#pragma unroll
  for (int mt = 0; mt < 2; ++mt)
#pragma unroll
    for (int ht = 0; ht < 8; ++ht)
      acc[mt][ht] = (f32x4){0.f, 0.f, 0.f, 0.f};

#pragma unroll
  for (int ks = 0; ks < 4; ++ks) {
    const int d0 = ks * 32 + g * 8;
    f32x4 xa0 = *(const f32x4*)(xrow + d0);
    f32x4 xa1 = *(const f32x4*)(xrow + d0 + 4);

    short8 dhi[2], dlo[2];            // diff fragments (B-operand: col = lane&15 = m)
#pragma unroll
    for (int mt = 0; mt < 2; ++mt) {
      const int m = m0 + mt * 16 + c;
      const float* yrow = y + (size_t)(b * M_ + m) * D_ + d0;
      f32x4 ya0 = *(const f32x4*)(yrow);
      f32x4 ya1 = *(const f32x4*)(yrow + 4);
      unsigned h0, h1, h2, h3, l0, l1, l2, l3;
      split2(xa0.x - ya0.x, xa0.y - ya0.y, h0, l0);
      split2(xa0.z - ya0.z, xa0.w - ya0.w, h1, l1);
      split2(xa1.x - ya1.x, xa1.y - ya1.y, h2, l2);
      split2(xa1.z - ya1.z, xa1.w - ya1.w, h3, l3);
      u32x4 hw = (u32x4){h0, h1, h2, h3};
      u32x4 lw = (u32x4){l0, l1, l2, l3};
      dhi[mt] = __builtin_bit_cast(short8, hw);
      dlo[mt] = __builtin_bit_cast(short8, lw);
    }

    const char* base = smem + ((size_t)(ks * 8) * 64 + lane) * 16;
#pragma unroll
    for (int htp = 0; htp < 4; ++htp) {
      const int h0 = 2 * htp, h1 = 2 * htp + 1;
      const short8 wh0 = *(const short8*)(base + h0 * 1024);
      const short8 wh1 = *(const short8*)(base + h1 * 1024);
      const short8 wl0 = *(const short8*)(base + 32768 + h0 * 1024);
      const short8 wl1 = *(const short8*)(base + 32768 + h1 * 1024);
      // D = W^T (A) x diff^T (B); pass-major: dependent acc reuses 4 apart
      acc[0][h0] = __builtin_amdgcn_mfma_f32_16x16x32_bf16(wh0, dhi[0], acc[0][h0], 0, 0, 0);
      acc[1][h0] = __builtin_amdgcn_mfma_f32_16x16x32_bf16(wh0, dhi[1], acc[1][h0], 0, 0, 0);
      acc[0][h1] = __builtin_amdgcn_mfma_f32_16x16x32_bf16(wh1, dhi[0], acc[0][h1], 0, 0, 0);
      acc[1][h1] = __builtin_amdgcn_mfma_f32_16x16x32_bf16(wh1, dhi[1], acc[1][h1], 0, 0, 0);
      acc[0][h0] = __builtin_amdgcn_mfma_f32_16x16x32_bf16(wh0, dlo[0], acc[0][h0], 0, 0, 0);
      acc[1][h0] = __builtin_amdgcn_mfma_f32_16x16x32_bf16(wh0, dlo[1], acc[1][h0], 0, 0, 0);
      acc[0][h1] = __builtin_amdgcn_mfma_f32_16x16x32_bf16(wh1, dlo[0], acc[0][h1], 0, 0, 0);
      acc[1][h1] = __builtin_amdgcn_mfma_f32_16x16x32_bf16(wh1, dlo[1], acc[1][h1], 0, 0, 0);
      acc[0][h0] = __builtin_amdgcn_mfma_f32_16x16x32_bf16(wl0, dhi[0], acc[0][h0], 0, 0, 0);
      acc[1][h0] = __builtin_amdgcn_mfma_f32_16x16x32_bf16(wl0, dhi[1], acc[1][h0], 0, 0, 0);
      acc[0][h1] = __builtin_amdgcn_mfma_f32_16x16x32_bf16(wl1, dhi[0], acc[0][h1], 0, 0, 0);
      acc[1][h1] = __builtin_amdgcn_mfma_f32_16x16x32_bf16(wl1, dhi[1], acc[1][h1], 0, 0, 0);
    }
  }

  // ---------------- epilogue (lane-local over h) ----------------
  // lane holds h = ht*16 + g*4 + r  (ht=0..7, r=0..3) for m = m0 + mt*16 + c
  const float* cxn = cx + (size_t)(b * N_ + n) * H_ + g * 4;
  f32x4 cxv[8], gv[8], bev[8], w2v[8];
#pragma unroll
  for (int ht = 0; ht < 8; ++ht) {
    cxv[ht] = *(const f32x4*)(cxn + ht * 16);
    gv[ht]  = *(const f32x4*)(gamma + g * 4 + ht * 16);
    bev[ht] = *(const f32x4*)(beta  + g * 4 + ht * 16);
    w2v[ht] = *(const f32x4*)(W2    + g * 4 + ht * 16);
  }
  const float b2v = b2[0];

#pragma unroll
  for (int mt = 0; mt < 2; ++mt) {
    const int m = m0 + mt * 16 + c;
    const float* cyrow = cy + (size_t)(b * M_ + m) * H_ + g * 4;
    f32x4 v[8];
    float s1 = 0.f, s2 = 0.f;
#pragma unroll
    for (int ht = 0; ht < 8; ++ht) {
      const f32x4 cyv = *(const f32x4*)(cyrow + ht * 16);
      f32x4 t = acc[mt][ht];
#pragma unroll
      for (int r = 0; r < 4; ++r) {
        t[r] += cxv[ht][r] + cyv[r];
        s1 += t[r];
        s2 = fmaf(t[r], t[r], s2);
      }
      v[ht] = t;
    }
    s1 += __shfl_xor(s1, 16); s1 += __shfl_xor(s1, 32);
    s2 += __shfl_xor(s2, 16); s2 += __shfl_xor(s2, 32);
    const float mu = s1 * (1.f / 128.f);
    const float var = s2 * (1.f / 128.f) - mu * mu;
    const float rs = rsqrtf(var + EPS);
    float o = 0.f;
#pragma unroll
    for (int ht = 0; ht < 8; ++ht) {
#pragma unroll
      for (int r = 0; r < 4; ++r) {
        const float hn = fmaf(v[ht][r] - mu, gv[ht][r] * rs, bev[ht][r]);
        o = fmaf(fmaxf(hn, 0.f), w2v[ht][r], o);
      }
    }
    o += __shfl_xor(o, 16); o += __shfl_xor(o, 32);
    if (g == 0)
      out[(size_t)(b * N_ + n) * M_ + m] = fmaxf(o + b2v, 0.f);
  }
}

extern "C" void kernel_launch(void* const* d_in, const int* in_sizes, int n_in,
                              void* d_out, int out_size, void* d_ws, size_t ws_size,
                              hipStream_t stream) {
  const float* x     = (const float*)d_in[0];
  const float* y     = (const float*)d_in[1];
  const float* W1    = (const float*)d_in[2];
  const float* b1    = (const float*)d_in[3];
  const float* gamma = (const float*)d_in[4];
  const float* beta  = (const float*)d_in[5];
  const float* W2    = (const float*)d_in[6];
  const float* b2    = (const float*)d_in[7];
  float* out = (float*)d_out;

  char* ws = (char*)d_ws;
  float* cx = (float*)ws;                                  // 1MB
  float* cy = (float*)(ws + (1 << 20));                    // 1MB
  unsigned short* bhi = (unsigned short*)(ws + (2 << 20)); // 32KB
  unsigned short* blo = bhi + 16384;                       // contiguous 32KB

  prep_all<<<dim3(2112), dim3(256), 0, stream>>>(x, y, W1, b1, cx, cy, bhi, blo);
  fused_main<<<dim3(M_ / 128, N_ / 2, B_), dim3(512), 0, stream>>>(
      x, y, gamma, beta, W2, b2, cx, cy, bhi, out);
}

// Round 5
// 242.899 us; speedup vs baseline: 1.4737x; 1.4737x over previous
//
#include <hip/hip_runtime.h>

#define B_  4
#define N_  512
#define M_  512
#define D_  128
#define H_  128
#define EPS 1e-5f

typedef __attribute__((ext_vector_type(8))) short short8;
typedef __attribute__((ext_vector_type(4))) float f32x4;
typedef __attribute__((ext_vector_type(4))) unsigned u32x4;

__device__ __forceinline__ unsigned short f2bf(float f){
  unsigned u = __float_as_uint(f);
  u += 0x7fffu + ((u >> 16) & 1u);          // round-to-nearest-even
  return (unsigned short)(u >> 16);
}
__device__ __forceinline__ float bf2f(unsigned short s){
  return __uint_as_float(((unsigned)s) << 16);
}

// hi/lo bf16 split of |d0|,|d1| packed into dwords.
__device__ __forceinline__ void split2(float d0, float d1, unsigned &hp, unsigned &lp){
  unsigned a0 = __float_as_uint(d0) & 0x7fffffffu;   // |d|
  unsigned a1 = __float_as_uint(d1) & 0x7fffffffu;
  unsigned r0 = a0 + 0x8000u;                        // round half up to bf16
  unsigned r1 = a1 + 0x8000u;
  hp = __builtin_amdgcn_perm(r1, r0, 0x07060302u);   // pack top16(r0)|top16(r1)
  float lo0 = __uint_as_float(a0) - __uint_as_float(r0 & 0xffff0000u);
  float lo1 = __uint_as_float(a1) - __uint_as_float(r1 & 0xffff0000u);
  unsigned t;
  asm("v_cvt_pk_bf16_f32 %0, %1, %2" : "=v"(t) : "v"(lo0), "v"(lo1));
  lp = t;
}

// ---------------- merged prep ----------------
__global__ __launch_bounds__(256) void prep_all(
    const float* __restrict__ x, const float* __restrict__ y,
    const float* __restrict__ W1, const float* __restrict__ b1,
    float* __restrict__ cx, float* __restrict__ cy,
    unsigned short* __restrict__ bhi, unsigned short* __restrict__ blo)
{
  const int blk = blockIdx.x;
  if (blk < 2048) {
    const int row = blk * 2 + (threadIdx.x >> 7);   // 0..4095
    const int h = threadIdx.x & 127;
    const bool isX = row < B_ * N_;
    const int r = isX ? row : row - B_ * N_;
    const float* src = (isX ? x : y) + (size_t)r * D_;
    const float* W = W1 + (isX ? 0 : D_ * H_);
    float acc = isX ? b1[h] : 0.f;
#pragma unroll
    for (int d0 = 0; d0 < D_; d0 += 4) {
      const f32x4 s = *(const f32x4*)(src + d0);
      acc = fmaf(s.x, W[(d0 + 0) * H_ + h], acc);
      acc = fmaf(s.y, W[(d0 + 1) * H_ + h], acc);
      acc = fmaf(s.z, W[(d0 + 2) * H_ + h], acc);
      acc = fmaf(s.w, W[(d0 + 3) * H_ + h], acc);
    }
    (isX ? cx : cy)[(size_t)r * H_ + h] = acc;
  } else {
    const int t = (blk - 2048) * 256 + threadIdx.x;   // 0..16383
    const int i    = t & 7;
    const int lane = (t >> 3) & 63;
    const int ht   = (t >> 9) & 7;
    const int ks   = t >> 12;
    const int k = ks * 32 + ((lane >> 4) << 3) + i;
    const int h = ht * 16 + (lane & 15);
    const float v = W1[(size_t)(2 * D_ + k) * H_ + h];
    const unsigned short hi = f2bf(v);
    bhi[t] = hi;
    blo[t] = f2bf(v - bf2f(hi));
  }
}

// ---------------- main fused kernel ----------------
// grid: (mblock=4, npair=256, b=4), 512 threads = 8 waves.
// waves 0-3 -> n = 2*npair, waves 4-7 -> n = 2*npair+1 (shared LDS B-stage).
// OPERAND-SWAPPED MFMA: D[h,m] = W1d^T x diff^T; lane holds 32 h-values
// for one m. cx+cy are folded into the MFMA C-in, so the epilogue is
// read-acc-in-place LN with near-zero extra registers (R4 spill lesson).
__global__ __launch_bounds__(512, 4) void fused_main(
    const float* __restrict__ x, const float* __restrict__ y,
    const float* __restrict__ gamma, const float* __restrict__ beta,
    const float* __restrict__ W2, const float* __restrict__ b2,
    const float* __restrict__ cx, const float* __restrict__ cy,
    const unsigned short* __restrict__ bhi, float* __restrict__ out)
{
  __shared__ char smem[65536];           // [hi 32KB][lo 32KB] fragment order

  const int tid = threadIdx.x;
  const int mblock = blockIdx.x, b = blockIdx.z;

  {
    const f32x4* src = (const f32x4*)bhi;   // bhi||blo contiguous 64KB
    f32x4* dst = (f32x4*)smem;
#pragma unroll
    for (int i = 0; i < 8; ++i)
      dst[i * 512 + tid] = src[i * 512 + tid];
  }
  __syncthreads();

  const int wave = tid >> 6, lane = tid & 63, g = lane >> 4, c = lane & 15;
  const int n = blockIdx.y * 2 + (wave >> 2);
  const int m0 = mblock * 128 + (wave & 3) * 32;
  const float* xrow = x + (size_t)(b * N_ + n) * D_;

  // acc init = cx[n,h] + cy[m,h]  (C-in of the MFMA chain).
  // lane (g,c), acc[mt][ht][r] <-> h = ht*16 + g*4 + r, m = m0 + mt*16 + c.
  f32x4 acc[2][8];
  {
    const float* cxn = cx + (size_t)(b * N_ + n) * H_ + g * 4;
    const float* cy0 = cy + (size_t)(b * M_ + m0 + c) * H_ + g * 4;
    const float* cy1 = cy0 + 16 * H_;
#pragma unroll
    for (int ht = 0; ht < 8; ++ht) {
      const f32x4 cx4 = *(const f32x4*)(cxn + ht * 16);
      acc[0][ht] = cx4 + *(const f32x4*)(cy0 + ht * 16);
      acc[1][ht] = cx4 + *(const f32x4*)(cy1 + ht * 16);
    }
  }

#pragma unroll
  for (int ks = 0; ks < 4; ++ks) {
    const int d0 = ks * 32 + g * 8;
    f32x4 xa0 = *(const f32x4*)(xrow + d0);
    f32x4 xa1 = *(const f32x4*)(xrow + d0 + 4);

    short8 dhi[2], dlo[2];            // diff fragments (B-operand: col = lane&15 = m)
#pragma unroll
    for (int mt = 0; mt < 2; ++mt) {
      const int m = m0 + mt * 16 + c;
      const float* yrow = y + (size_t)(b * M_ + m) * D_ + d0;
      f32x4 ya0 = *(const f32x4*)(yrow);
      f32x4 ya1 = *(const f32x4*)(yrow + 4);
      unsigned h0, h1, h2, h3, l0, l1, l2, l3;
      split2(xa0.x - ya0.x, xa0.y - ya0.y, h0, l0);
      split2(xa0.z - ya0.z, xa0.w - ya0.w, h1, l1);
      split2(xa1.x - ya1.x, xa1.y - ya1.y, h2, l2);
      split2(xa1.z - ya1.z, xa1.w - ya1.w, h3, l3);
      u32x4 hw = (u32x4){h0, h1, h2, h3};
      u32x4 lw = (u32x4){l0, l1, l2, l3};
      dhi[mt] = __builtin_bit_cast(short8, hw);
      dlo[mt] = __builtin_bit_cast(short8, lw);
    }

    const char* base = smem + ((size_t)(ks * 8) * 64 + lane) * 16;
#pragma unroll
    for (int htp = 0; htp < 4; ++htp) {
      const int h0 = 2 * htp, h1 = 2 * htp + 1;
      const short8 wh0 = *(const short8*)(base + h0 * 1024);
      const short8 wh1 = *(const short8*)(base + h1 * 1024);
      const short8 wl0 = *(const short8*)(base + 32768 + h0 * 1024);
      const short8 wl1 = *(const short8*)(base + 32768 + h1 * 1024);
      // D = W^T (A) x diff^T (B); pass-major: dependent acc reuses 4 apart
      acc[0][h0] = __builtin_amdgcn_mfma_f32_16x16x32_bf16(wh0, dhi[0], acc[0][h0], 0, 0, 0);
      acc[1][h0] = __builtin_amdgcn_mfma_f32_16x16x32_bf16(wh0, dhi[1], acc[1][h0], 0, 0, 0);
      acc[0][h1] = __builtin_amdgcn_mfma_f32_16x16x32_bf16(wh1, dhi[0], acc[0][h1], 0, 0, 0);
      acc[1][h1] = __builtin_amdgcn_mfma_f32_16x16x32_bf16(wh1, dhi[1], acc[1][h1], 0, 0, 0);
      acc[0][h0] = __builtin_amdgcn_mfma_f32_16x16x32_bf16(wh0, dlo[0], acc[0][h0], 0, 0, 0);
      acc[1][h0] = __builtin_amdgcn_mfma_f32_16x16x32_bf16(wh0, dlo[1], acc[1][h0], 0, 0, 0);
      acc[0][h1] = __builtin_amdgcn_mfma_f32_16x16x32_bf16(wh1, dlo[0], acc[0][h1], 0, 0, 0);
      acc[1][h1] = __builtin_amdgcn_mfma_f32_16x16x32_bf16(wh1, dlo[1], acc[1][h1], 0, 0, 0);
      acc[0][h0] = __builtin_amdgcn_mfma_f32_16x16x32_bf16(wl0, dhi[0], acc[0][h0], 0, 0, 0);
      acc[1][h0] = __builtin_amdgcn_mfma_f32_16x16x32_bf16(wl0, dhi[1], acc[1][h0], 0, 0, 0);
      acc[0][h1] = __builtin_amdgcn_mfma_f32_16x16x32_bf16(wl1, dhi[0], acc[0][h1], 0, 0, 0);
      acc[1][h1] = __builtin_amdgcn_mfma_f32_16x16x32_bf16(wl1, dhi[1], acc[1][h1], 0, 0, 0);
    }
  }

  // ---------------- epilogue: LN stats in place, then fused pass2 ----------------
  float s1a = 0.f, s2a = 0.f, s1b = 0.f, s2b = 0.f;
#pragma unroll
  for (int ht = 0; ht < 8; ++ht) {
#pragma unroll
    for (int r = 0; r < 4; ++r) {
      const float va = acc[0][ht][r], vb = acc[1][ht][r];
      s1a += va; s2a = fmaf(va, va, s2a);
      s1b += vb; s2b = fmaf(vb, vb, s2b);
    }
  }
  s1a += __shfl_xor(s1a, 16); s1a += __shfl_xor(s1a, 32);
  s2a += __shfl_xor(s2a, 16); s2a += __shfl_xor(s2a, 32);
  s1b += __shfl_xor(s1b, 16); s1b += __shfl_xor(s1b, 32);
  s2b += __shfl_xor(s2b, 16); s2b += __shfl_xor(s2b, 32);
  const float mua = s1a * (1.f / 128.f);
  const float rsa = rsqrtf(s2a * (1.f / 128.f) - mua * mua + EPS);
  const float mub = s1b * (1.f / 128.f);
  const float rsb = rsqrtf(s2b * (1.f / 128.f) - mub * mub + EPS);

  float oa = 0.f, ob = 0.f;
#pragma unroll
  for (int ht = 0; ht < 8; ++ht) {
    const f32x4 g4 = *(const f32x4*)(gamma + g * 4 + ht * 16);
    const f32x4 b4 = *(const f32x4*)(beta  + g * 4 + ht * 16);
    const f32x4 w4 = *(const f32x4*)(W2    + g * 4 + ht * 16);
#pragma unroll
    for (int r = 0; r < 4; ++r) {
      const float hna = fmaf(acc[0][ht][r] - mua, g4[r] * rsa, b4[r]);
      const float hnb = fmaf(acc[1][ht][r] - mub, g4[r] * rsb, b4[r]);
      oa = fmaf(fmaxf(hna, 0.f), w4[r], oa);
      ob = fmaf(fmaxf(hnb, 0.f), w4[r], ob);
    }
  }
  oa += __shfl_xor(oa, 16); oa += __shfl_xor(oa, 32);
  ob += __shfl_xor(ob, 16); ob += __shfl_xor(ob, 32);
  const float b2v = b2[0];
  if (g == 0) {
    float* orow = out + (size_t)(b * N_ + n) * M_ + m0 + c;
    orow[0]  = fmaxf(oa + b2v, 0.f);
    orow[16] = fmaxf(ob + b2v, 0.f);
  }
}

extern "C" void kernel_launch(void* const* d_in, const int* in_sizes, int n_in,
                              void* d_out, int out_size, void* d_ws, size_t ws_size,
                              hipStream_t stream) {
  const float* x     = (const float*)d_in[0];
  const float* y     = (const float*)d_in[1];
  const float* W1    = (const float*)d_in[2];
  const float* b1    = (const float*)d_in[3];
  const float* gamma = (const float*)d_in[4];
  const float* beta  = (const float*)d_in[5];
  const float* W2    = (const float*)d_in[6];
  const float* b2    = (const float*)d_in[7];
  float* out = (float*)d_out;

  char* ws = (char*)d_ws;
  float* cx = (float*)ws;                                  // 1MB
  float* cy = (float*)(ws + (1 << 20));                    // 1MB
  unsigned short* bhi = (unsigned short*)(ws + (2 << 20)); // 32KB
  unsigned short* blo = bhi + 16384;                       // contiguous 32KB

  prep_all<<<dim3(2112), dim3(256), 0, stream>>>(x, y, W1, b1, cx, cy, bhi, blo);
  fused_main<<<dim3(M_ / 128, N_ / 2, B_), dim3(512), 0, stream>>>(
      x, y, gamma, beta, W2, b2, cx, cy, bhi, out);
}